// Round 3
// baseline (409.656 us; speedup 1.0000x reference)
//
#include <hip/hip_runtime.h>
#include <math.h>

#define N 4096

typedef float f32x4 __attribute__((ext_vector_type(4)));

// ---------------------------------------------------------------------------
// Fused layer: one block per output row p.
//   1) post[p] = act( dot(W[p], pre) + b[p] )     (block-wide reduce)
//   2) outW[p][q] = 2*A*(B*pre[q]*post[p] + C*pre[q] + D*post[p] + E)
// mode 0: act = tanh;  mode 1: y_out[p] = v, act = sigmoid.
// H is streamed once -> non-temporal loads; outW written once -> NT stores.
// ---------------------------------------------------------------------------
__global__ __launch_bounds__(256) void fused_layer(const float* __restrict__ W,
                                                   const float* __restrict__ b,
                                                   const float* __restrict__ H,
                                                   const float* __restrict__ pre,
                                                   float* __restrict__ post_out,
                                                   float* __restrict__ y_out,
                                                   float* __restrict__ outW,
                                                   int mode) {
    const int p   = blockIdx.x;
    const int tid = threadIdx.x;

    __shared__ float red[4];
    __shared__ float s_post;

    const f32x4* xv   = reinterpret_cast<const f32x4*>(pre);
    const float* Hrow = H + (size_t)p * N * 5;
    float*       Orow = outW + (size_t)p * N;

    // --- prefetch round-0 hebb data (independent of the dot) ---
    const int q0_0 = tid * 4;
    const f32x4* h4_0 = reinterpret_cast<const f32x4*>(Hrow + (size_t)q0_0 * 5);
    f32x4 f0 = __builtin_nontemporal_load(h4_0 + 0);
    f32x4 f1 = __builtin_nontemporal_load(h4_0 + 1);
    f32x4 f2 = __builtin_nontemporal_load(h4_0 + 2);
    f32x4 f3 = __builtin_nontemporal_load(h4_0 + 3);
    f32x4 f4 = __builtin_nontemporal_load(h4_0 + 4);
    f32x4 pr0 = xv[tid];

    // --- dot(W[p], pre) ---
    const f32x4* Wr = reinterpret_cast<const f32x4*>(W + (size_t)p * N);
    float acc = 0.0f;
#pragma unroll
    for (int i = 0; i < 4; ++i) {
        const int j = tid + i * 256;
        f32x4 w4 = Wr[j];
        f32x4 x4 = xv[j];
        acc += w4.x * x4.x + w4.y * x4.y + w4.z * x4.z + w4.w * x4.w;
    }
#pragma unroll
    for (int off = 32; off > 0; off >>= 1)
        acc += __shfl_down(acc, off, 64);
    const int lane = tid & 63;
    const int wave = tid >> 6;
    if (lane == 0) red[wave] = acc;
    __syncthreads();
    if (tid == 0) {
        const float v = red[0] + red[1] + red[2] + red[3] + b[p];
        float post;
        if (mode == 0) {
            post = tanhf(v);
        } else {
            y_out[p] = v;
            post = 1.0f / (1.0f + expf(-v));
        }
        post_out[p] = post;
        s_post = post;
    }
    __syncthreads();
    const float po = s_post;

    // --- hebb row: round 0 from prefetched regs ---
    {
        f32x4 o;
        o.x = 2.0f * f0.x * (f0.y * pr0.x * po + f0.z * pr0.x + f0.w * po + f1.x);
        o.y = 2.0f * f1.y * (f1.z * pr0.y * po + f1.w * pr0.y + f2.x * po + f2.y);
        o.z = 2.0f * f2.z * (f2.w * pr0.z * po + f3.x * pr0.z + f3.y * po + f3.z);
        o.w = 2.0f * f3.w * (f4.x * pr0.w * po + f4.y * pr0.w + f4.z * po + f4.w);
        __builtin_nontemporal_store(o, reinterpret_cast<f32x4*>(Orow + q0_0));
    }

    // --- rounds 1..3 ---
#pragma unroll
    for (int r = 1; r < 4; ++r) {
        const int g  = tid + r * 256;   // 4-q group index
        const int q0 = g * 4;
        const f32x4* h4 = reinterpret_cast<const f32x4*>(Hrow + (size_t)q0 * 5);
        f32x4 v0 = __builtin_nontemporal_load(h4 + 0);
        f32x4 v1 = __builtin_nontemporal_load(h4 + 1);
        f32x4 v2 = __builtin_nontemporal_load(h4 + 2);
        f32x4 v3 = __builtin_nontemporal_load(h4 + 3);
        f32x4 v4 = __builtin_nontemporal_load(h4 + 4);
        f32x4 pr = xv[g];

        f32x4 o;
        o.x = 2.0f * v0.x * (v0.y * pr.x * po + v0.z * pr.x + v0.w * po + v1.x);
        o.y = 2.0f * v1.y * (v1.z * pr.y * po + v1.w * pr.y + v2.x * po + v2.y);
        o.z = 2.0f * v2.z * (v2.w * pr.z * po + v3.x * pr.z + v3.y * po + v3.z);
        o.w = 2.0f * v3.w * (v4.x * pr.w * po + v4.y * pr.w + v4.z * po + v4.w);
        __builtin_nontemporal_store(o, reinterpret_cast<f32x4*>(Orow + q0));
    }
}

// ---------------------------------------------------------------------------
// d_in: x, W0, b0, H0, W1, b1, H1, W2, b2, H2
// d_out: y (4096) | new_W0 | new_W1 | new_W2   (all f32)
// ---------------------------------------------------------------------------
extern "C" void kernel_launch(void* const* d_in, const int* in_sizes, int n_in,
                              void* d_out, int out_size, void* d_ws, size_t ws_size,
                              hipStream_t stream) {
    const float* x  = (const float*)d_in[0];
    const float* W0 = (const float*)d_in[1];
    const float* b0 = (const float*)d_in[2];
    const float* H0 = (const float*)d_in[3];
    const float* W1 = (const float*)d_in[4];
    const float* b1 = (const float*)d_in[5];
    const float* H1 = (const float*)d_in[6];
    const float* W2 = (const float*)d_in[7];
    const float* b2 = (const float*)d_in[8];
    const float* H2 = (const float*)d_in[9];

    float* out = (float*)d_out;
    float* y   = out;                          // 4096
    float* oW0 = out + N;                      // 4096*4096
    float* oW1 = oW0 + (size_t)N * N;
    float* oW2 = oW1 + (size_t)N * N;

    float* s  = (float*)d_ws;
    float* s1 = s;          // tanh layer-0 output
    float* s2 = s + N;      // tanh layer-1 output
    float* s3 = s + 2 * N;  // sigmoid(y) (unused downstream, but harmless)

    const dim3 grid(N), block(256);

    hipLaunchKernelGGL(fused_layer, grid, block, 0, stream, W0, b0, H0, x,  s1, (float*)nullptr, oW0, 0);
    hipLaunchKernelGGL(fused_layer, grid, block, 0, stream, W1, b1, H1, s1, s2, (float*)nullptr, oW1, 0);
    hipLaunchKernelGGL(fused_layer, grid, block, 0, stream, W2, b2, H2, s2, s3, y,               oW2, 1);
}

// Round 4
// 255.447 us; speedup vs baseline: 1.6037x; 1.6037x over previous
//
#include <hip/hip_runtime.h>
#include <math.h>

#define N 4096

typedef float f32x4 __attribute__((ext_vector_type(4)));

// ---------------------------------------------------------------------------
// Matvec: one block (256 thr) per output row. out[p] = act(dot(W[p],x)+b[p]).
// mode 0: out = tanh(v);  mode 1: y_out[p] = v, out = sigmoid(v).
// ---------------------------------------------------------------------------
__global__ __launch_bounds__(256) void mv_kernel(const float* __restrict__ W,
                                                 const float* __restrict__ b,
                                                 const float* __restrict__ x,
                                                 float* __restrict__ out,
                                                 float* __restrict__ y_out,
                                                 int mode) {
    const int p   = blockIdx.x;
    const int tid = threadIdx.x;
    __shared__ float red[4];

    const f32x4* xv = reinterpret_cast<const f32x4*>(x);
    const f32x4* Wr = reinterpret_cast<const f32x4*>(W + (size_t)p * N);

    float acc = 0.0f;
#pragma unroll
    for (int i = 0; i < 4; ++i) {
        const int j = tid + i * 256;
        f32x4 w4 = Wr[j];
        f32x4 x4 = xv[j];
        acc += w4.x * x4.x + w4.y * x4.y + w4.z * x4.z + w4.w * x4.w;
    }
#pragma unroll
    for (int off = 32; off > 0; off >>= 1)
        acc += __shfl_down(acc, off, 64);
    if ((tid & 63) == 0) red[tid >> 6] = acc;
    __syncthreads();
    if (tid == 0) {
        const float v = red[0] + red[1] + red[2] + red[3] + b[p];
        if (mode == 0) {
            out[p] = tanhf(v);
        } else {
            y_out[p] = v;
            out[p]   = 1.0f / (1.0f + expf(-v));
        }
    }
}

// ---------------------------------------------------------------------------
// All three Hebbian updates in one dispatch. Exact R1 hebb body (6.4 TB/s),
// layer selected by block index. 16384 blocks per layer; thread owns 4 q's.
// ---------------------------------------------------------------------------
__global__ __launch_bounds__(256) void hebb_all(const float* __restrict__ H0,
                                                const float* __restrict__ H1,
                                                const float* __restrict__ H2,
                                                const float* __restrict__ pre0,
                                                const float* __restrict__ pre1,
                                                const float* __restrict__ pre2,
                                                const float* __restrict__ post0,
                                                const float* __restrict__ post1,
                                                const float* __restrict__ post2,
                                                float* __restrict__ o0,
                                                float* __restrict__ o1,
                                                float* __restrict__ o2) {
    const int L    = blockIdx.x >> 14;     // 16384 blocks per layer
    const int bidx = blockIdx.x & 16383;

    const float* H;  const float* pre;  const float* post;  float* outW;
    if (L == 0)      { H = H0; pre = pre0; post = post0; outW = o0; }
    else if (L == 1) { H = H1; pre = pre1; post = post1; outW = o1; }
    else             { H = H2; pre = pre2; post = post2; outW = o2; }

    const int idx = bidx * 256 + threadIdx.x;  // one per 4 q's
    const int p   = idx >> 10;
    const int q0  = (idx & 1023) << 2;

    const size_t base = ((size_t)p * N + q0) * 5;
    const f32x4* h4   = reinterpret_cast<const f32x4*>(H + base);
    f32x4 v0 = h4[0];
    f32x4 v1 = h4[1];
    f32x4 v2 = h4[2];
    f32x4 v3 = h4[3];
    f32x4 v4 = h4[4];

    const float po = post[p];
    const f32x4 pr = *reinterpret_cast<const f32x4*>(pre + q0);

    f32x4 o;
    o.x = 2.0f * v0.x * (v0.y * pr.x * po + v0.z * pr.x + v0.w * po + v1.x);
    o.y = 2.0f * v1.y * (v1.z * pr.y * po + v1.w * pr.y + v2.x * po + v2.y);
    o.z = 2.0f * v2.z * (v2.w * pr.z * po + v3.x * pr.z + v3.y * po + v3.z);
    o.w = 2.0f * v3.w * (v4.x * pr.w * po + v4.y * pr.w + v4.z * po + v4.w);

    *reinterpret_cast<f32x4*>(outW + (size_t)p * N + q0) = o;
}

// ---------------------------------------------------------------------------
// d_in: x, W0, b0, H0, W1, b1, H1, W2, b2, H2
// d_out: y (4096) | new_W0 | new_W1 | new_W2   (all f32)
// ---------------------------------------------------------------------------
extern "C" void kernel_launch(void* const* d_in, const int* in_sizes, int n_in,
                              void* d_out, int out_size, void* d_ws, size_t ws_size,
                              hipStream_t stream) {
    const float* x  = (const float*)d_in[0];
    const float* W0 = (const float*)d_in[1];
    const float* b0 = (const float*)d_in[2];
    const float* H0 = (const float*)d_in[3];
    const float* W1 = (const float*)d_in[4];
    const float* b1 = (const float*)d_in[5];
    const float* H1 = (const float*)d_in[6];
    const float* W2 = (const float*)d_in[7];
    const float* b2 = (const float*)d_in[8];
    const float* H2 = (const float*)d_in[9];

    float* out = (float*)d_out;
    float* y   = out;                          // 4096
    float* oW0 = out + N;                      // 4096*4096
    float* oW1 = oW0 + (size_t)N * N;
    float* oW2 = oW1 + (size_t)N * N;

    float* s  = (float*)d_ws;
    float* s1 = s;          // tanh layer-0 output
    float* s2 = s + N;      // tanh layer-1 output
    float* s3 = s + 2 * N;  // sigmoid(y)

    const dim3 mvGrid(N), mvBlock(256);

    hipLaunchKernelGGL(mv_kernel, mvGrid, mvBlock, 0, stream, W0, b0, x,  s1, (float*)nullptr, 0);
    hipLaunchKernelGGL(mv_kernel, mvGrid, mvBlock, 0, stream, W1, b1, s1, s2, (float*)nullptr, 0);
    hipLaunchKernelGGL(mv_kernel, mvGrid, mvBlock, 0, stream, W2, b2, s2, s3, y, 1);

    const dim3 hGrid(3 * 16384), hBlock(256);
    hipLaunchKernelGGL(hebb_all, hGrid, hBlock, 0, stream,
                       H0, H1, H2, x, s1, s2, s1, s2, s3, oW0, oW1, oW2);
}

// Round 5
// 255.099 us; speedup vs baseline: 1.6059x; 1.0014x over previous
//
#include <hip/hip_runtime.h>
#include <math.h>

#define N 4096

typedef float f32x4 __attribute__((ext_vector_type(4)));

// ---------------------------------------------------------------------------
// One row of matvec, computed by the whole 256-thread block.
// out[p] = act(dot(W[p], x) + b[p]); mode 0: tanh; mode 1: y=v, out=sigmoid.
// ---------------------------------------------------------------------------
__device__ __forceinline__ void mv_row(const float* __restrict__ W,
                                       const float* __restrict__ b,
                                       const float* __restrict__ x,
                                       float* __restrict__ out,
                                       float* __restrict__ y_out,
                                       int p, int mode, float* red) {
    const int tid = threadIdx.x;
    const f32x4* xv = reinterpret_cast<const f32x4*>(x);
    const f32x4* Wr = reinterpret_cast<const f32x4*>(W + (size_t)p * N);

    float acc = 0.0f;
#pragma unroll
    for (int i = 0; i < 4; ++i) {
        const int j = tid + i * 256;
        f32x4 w4 = Wr[j];
        f32x4 x4 = xv[j];
        acc += w4.x * x4.x + w4.y * x4.y + w4.z * x4.z + w4.w * x4.w;
    }
#pragma unroll
    for (int off = 32; off > 0; off >>= 1)
        acc += __shfl_down(acc, off, 64);
    if ((tid & 63) == 0) red[tid >> 6] = acc;
    __syncthreads();
    if (tid == 0) {
        const float v = red[0] + red[1] + red[2] + red[3] + b[p];
        if (mode == 0) {
            out[p] = tanhf(v);
        } else {
            y_out[p] = v;
            out[p]   = 1.0f / (1.0f + expf(-v));
        }
    }
    __syncthreads();   // red[] reused by the next row
}

// ---------------------------------------------------------------------------
// One 4-q Hebbian group (exact R1 body, 6.4 TB/s verified).
// ---------------------------------------------------------------------------
__device__ __forceinline__ void hebb_group(const float* __restrict__ H,
                                           const float* __restrict__ pre,
                                           const float* __restrict__ post,
                                           float* __restrict__ outW, int idx) {
    const int p  = idx >> 10;
    const int q0 = (idx & 1023) << 2;

    const size_t base = ((size_t)p * N + q0) * 5;
    const f32x4* h4   = reinterpret_cast<const f32x4*>(H + base);
    f32x4 v0 = h4[0];
    f32x4 v1 = h4[1];
    f32x4 v2 = h4[2];
    f32x4 v3 = h4[3];
    f32x4 v4 = h4[4];

    const float po = post[p];
    const f32x4 pr = *reinterpret_cast<const f32x4*>(pre + q0);

    f32x4 o;
    o.x = 2.0f * v0.x * (v0.y * pr.x * po + v0.z * pr.x + v0.w * po + v1.x);
    o.y = 2.0f * v1.y * (v1.z * pr.y * po + v1.w * pr.y + v2.x * po + v2.y);
    o.z = 2.0f * v2.z * (v2.w * pr.z * po + v3.x * pr.z + v3.y * po + v3.z);
    o.w = 2.0f * v3.w * (v4.x * pr.w * po + v4.y * pr.w + v4.z * po + v4.w);

    *reinterpret_cast<f32x4*>(outW + (size_t)p * N + q0) = o;
}

// ---------------------------------------------------------------------------
// Standalone matvec (layer 0): one block per row.
// ---------------------------------------------------------------------------
__global__ __launch_bounds__(256) void mv_kernel(const float* __restrict__ W,
                                                 const float* __restrict__ b,
                                                 const float* __restrict__ x,
                                                 float* __restrict__ out,
                                                 float* __restrict__ y_out,
                                                 int mode) {
    __shared__ float red[4];
    mv_row(W, b, x, out, y_out, blockIdx.x, mode, red);
}

// ---------------------------------------------------------------------------
// Fused dispatch: blocks [0,2048) run matvec layer L+1 (2 rows each),
// blocks [2048, 18432) run hebb layer L (independent of the matvec).
// ---------------------------------------------------------------------------
__global__ __launch_bounds__(256) void mv_hebb(const float* __restrict__ W,
                                               const float* __restrict__ b,
                                               const float* __restrict__ xin,
                                               float* __restrict__ mv_out,
                                               float* __restrict__ y_out,
                                               int mode,
                                               const float* __restrict__ H,
                                               const float* __restrict__ pre,
                                               const float* __restrict__ post,
                                               float* __restrict__ outW) {
    __shared__ float red[4];
    if (blockIdx.x < 2048) {
        mv_row(W, b, xin, mv_out, y_out, blockIdx.x * 2,     mode, red);
        mv_row(W, b, xin, mv_out, y_out, blockIdx.x * 2 + 1, mode, red);
    } else {
        const int idx = (blockIdx.x - 2048) * 256 + threadIdx.x;
        hebb_group(H, pre, post, outW, idx);
    }
}

// ---------------------------------------------------------------------------
// Standalone hebb (layer 2).
// ---------------------------------------------------------------------------
__global__ __launch_bounds__(256) void hebb_kernel(const float* __restrict__ H,
                                                   const float* __restrict__ pre,
                                                   const float* __restrict__ post,
                                                   float* __restrict__ outW) {
    const int idx = blockIdx.x * 256 + threadIdx.x;
    hebb_group(H, pre, post, outW, idx);
}

// ---------------------------------------------------------------------------
// d_in: x, W0, b0, H0, W1, b1, H1, W2, b2, H2
// d_out: y (4096) | new_W0 | new_W1 | new_W2   (all f32)
// Schedule: mv0 -> [mv1 || hebb0] -> [mv2 || hebb1] -> hebb2
// ---------------------------------------------------------------------------
extern "C" void kernel_launch(void* const* d_in, const int* in_sizes, int n_in,
                              void* d_out, int out_size, void* d_ws, size_t ws_size,
                              hipStream_t stream) {
    const float* x  = (const float*)d_in[0];
    const float* W0 = (const float*)d_in[1];
    const float* b0 = (const float*)d_in[2];
    const float* H0 = (const float*)d_in[3];
    const float* W1 = (const float*)d_in[4];
    const float* b1 = (const float*)d_in[5];
    const float* H1 = (const float*)d_in[6];
    const float* W2 = (const float*)d_in[7];
    const float* b2 = (const float*)d_in[8];
    const float* H2 = (const float*)d_in[9];

    float* out = (float*)d_out;
    float* y   = out;                          // 4096
    float* oW0 = out + N;                      // 4096*4096
    float* oW1 = oW0 + (size_t)N * N;
    float* oW2 = oW1 + (size_t)N * N;

    float* s  = (float*)d_ws;
    float* s1 = s;          // tanh layer-0 output
    float* s2 = s + N;      // tanh layer-1 output
    float* s3 = s + 2 * N;  // sigmoid(y)

    // D0: mv0 (s1 = tanh(W0 x + b0))
    hipLaunchKernelGGL(mv_kernel, dim3(N), dim3(256), 0, stream,
                       W0, b0, x, s1, (float*)nullptr, 0);

    // D1: mv1 (s2) || hebb0 (oW0 from H0, pre=x, post=s1)
    hipLaunchKernelGGL(mv_hebb, dim3(18432), dim3(256), 0, stream,
                       W1, b1, s1, s2, (float*)nullptr, 0,
                       H0, x, s1, oW0);

    // D2: mv2 (s3, y) || hebb1 (oW1 from H1, pre=s1, post=s2)
    hipLaunchKernelGGL(mv_hebb, dim3(18432), dim3(256), 0, stream,
                       W2, b2, s2, s3, y, 1,
                       H1, s1, s2, oW1);

    // D3: hebb2 (oW2 from H2, pre=s2, post=s3)
    hipLaunchKernelGGL(hebb_kernel, dim3(16384), dim3(256), 0, stream,
                       H2, s2, s3, oW2);
}